// Round 5
// baseline (140.994 us; speedup 1.0000x reference)
//
#include <hip/hip_runtime.h>

// Duration-based length regulation. B=8, T=512, D=512, MAX_LEN = T*15 = 7680.
// features fp32 (B,T,D), durations int32 (B,T), out fp32 (B,MAX_LEN,D).
//
// R11: kill the prologue. R4 (138.9us) = ~96us fixed harness poison fills
// + ~40us kernel vs ~22us streaming floor. The per-block 17-barrier LDS
// scan (redundant x2048) is replaced by a wave-0-only shfl scan (0 barriers,
// 1 __syncthreads total), and FPB doubles to 60 (1024 blocks) to halve
// prologue count. Copy loop is R4's verified run-detect contiguous stream.
#define BB 8
#define TT 512
#define DD 512
#define MAX_LEN 7680
#define FPB 60                        // frames per block
#define HPB (FPB / 2)                 // frames per 128-lane subgroup (30)
#define BPB (MAX_LEN / FPB)           // 128 blocks per batch

__global__ __launch_bounds__(256) void regulate_kernel(
    const float4* __restrict__ feat,   // (B, T, DD/4)
    const int*    __restrict__ dur,    // (B, T)
    float4*       __restrict__ out)    // (B, MAX_LEN, DD/4)
{
    __shared__ int idx_s[FPB];         // frame -> phoneme for this window

    const int t    = threadIdx.x;
    const int b    = blockIdx.x / BPB;
    const int base = (blockIdx.x % BPB) * FPB;
    const int lim  = base + FPB;

    // ---- prologue: wave 0 computes the full 512-cumsum via shfl scan ----
    if (t < 64) {
        const int l = t;
        // lane l owns phonemes 8l..8l+7: two aligned int4 loads
        const int4* d4 = (const int4*)(dur + b * TT + 8 * l);
        int4 a = d4[0], c = d4[1];
        int d[8] = {a.x, a.y, a.z, a.w, c.x, c.y, c.z, c.w};
        int s[8];
        int run = 0;
#pragma unroll
        for (int i = 0; i < 8; ++i) {
            int di = d[i] < 1 ? 1 : d[i];          // clamp(min=1)
            run += di;
            s[i] = run;                            // in-lane inclusive scan
        }
        // wave-inclusive scan of per-lane sums (6 shfl rounds, no barriers)
        int incl = run;
#pragma unroll
        for (int off = 1; off < 64; off <<= 1) {
            int v = __shfl_up(incl, off, 64);
            if (l >= off) incl += v;
        }
        const int pre = incl - run;                // exclusive prefix of lane

        // init window, then scatter (same-wave LDS ops are ordered)
        for (int j = l; j < FPB; j += 64) idx_s[j] = -1;
#pragma unroll
        for (int i = 0; i < 8; ++i) {
            int st = pre + (i ? s[i - 1] : 0);     // phoneme start frame
            int en = pre + s[i];                   // phoneme end frame
            st = st > base ? st : base;
            en = en < lim ? en : lim;
            for (int k = st; k < en; ++k) idx_s[k - base] = 8 * l + i;
        }
    }
    __syncthreads();                               // the only barrier

    // ---- run-detection streaming copy (verified R4 structure) ----
    const int lane = t & 127;                      // float4 column in 2 KB row
    const int sub  = t >> 7;                       // contiguous 30-frame range
    const int off  = sub * HPB;
    const float4* featb = feat + (size_t)b * TT * (DD / 4) + lane;
    float4*       outb  = out  + ((size_t)b * MAX_LEN + base + off) * (DD / 4) + lane;

    int    prev = -2;                              // force load on first iter
    float4 val  = make_float4(0.f, 0.f, 0.f, 0.f);
#pragma unroll
    for (int j = 0; j < HPB; ++j) {
        const int src = idx_s[off + j];            // LDS broadcast, wave-uniform
        if (src != prev) {                         // wave-uniform branch
            val = (src >= 0) ? featb[(size_t)src * (DD / 4)]
                             : make_float4(0.f, 0.f, 0.f, 0.f);
            prev = src;
        }
        outb[(size_t)j * (DD / 4)] = val;
    }
}

extern "C" void kernel_launch(void* const* d_in, const int* in_sizes, int n_in,
                              void* d_out, int out_size, void* d_ws, size_t ws_size,
                              hipStream_t stream) {
    // Select pointers by element count (features = B*T*D = 2097152, dur = 4096)
    const float* feat;
    const int*   dur;
    if (in_sizes[0] == BB * TT) {
        dur  = (const int*)d_in[0];
        feat = (const float*)d_in[1];
    } else {
        feat = (const float*)d_in[0];
        dur  = (const int*)d_in[1];
    }
    float* out = (float*)d_out;        // (B, MAX_LEN, D) fp32

    regulate_kernel<<<BB * BPB, 256, 0, stream>>>(
        (const float4*)feat, dur, (float4*)out);
}

// Round 6
// 130.715 us; speedup vs baseline: 1.0786x; 1.0786x over previous
//
#include <hip/hip_runtime.h>

// Duration-based length regulation. B=8, T=512, D=512, MAX_LEN = T*15 = 7680.
// features fp32 (B,T,D), durations int32 (B,T), out fp32 (B,MAX_LEN,D).
//
// R12: phoneme-parallel scatter formulation. R4/R5 post-mortems: scan and
// search structure are latency-hidden (both rewrites neutral); the cost is
// dependent gather loads inside the store stream (feat misses the 4MiB
// per-XCD L2 -> ~500cy LLC latency at every run boundary). Inverting the
// decomposition makes load addresses static per block: each block owns 4
// phonemes, issues both feature-row loads at cycle 0 (before the scan),
// then stores row x duration with ZERO loads in the stream. Padding is
// zero-stored, split evenly across the batch's blocks. No LDS, no barriers.
#define BB 8
#define TT 512
#define DD 512
#define MAX_LEN 7680
#define PPB 4                         // phonemes per block
#define BPB (TT / PPB)                // 128 blocks per batch

__global__ __launch_bounds__(256) void regulate_kernel(
    const float4* __restrict__ feat,   // (B, T, DD/4)
    const int*    __restrict__ dur,    // (B, T)
    float4*       __restrict__ out)    // (B, MAX_LEN, DD/4)
{
    const int t    = threadIdx.x;
    const int blk  = blockIdx.x & (BPB - 1);   // block within batch
    const int b    = blockIdx.x >> 7;          // batch (BPB = 128)
    const int lane = t & 127;                  // float4 column in 2 KB row
    const int sub  = t >> 7;                   // owns phonemes 2sub, 2sub+1
    const int l    = t & 63;                   // scan lane within wave

    // ---- issue ALL global loads up front (durations first, then rows) ----
    // lane l owns phonemes 8l..8l+7 of this batch for the scan
    const int4* d4p = (const int4*)(dur + b * TT + 8 * l);
    int4 da = d4p[0];
    int4 db = d4p[1];

    // this sub's two feature rows: addresses are STATIC (no scan needed)
    const int ph_a = PPB * blk + 2 * sub;
    const float4* featb = feat + (size_t)b * TT * (DD / 4) + lane;
    float4 va = featb[(size_t)ph_a * (DD / 4)];
    float4 vb = featb[(size_t)(ph_a + 1) * (DD / 4)];

    // ---- wave shfl scan over 512 clamped durations (verified R5 core) ----
    int d[8] = {da.x, da.y, da.z, da.w, db.x, db.y, db.z, db.w};
    int s[8];
    int run = 0;
#pragma unroll
    for (int i = 0; i < 8; ++i) {
        int di = d[i] < 1 ? 1 : d[i];          // clamp(min=1)
        run += di;
        s[i] = run;                            // in-lane inclusive scan
    }
    int incl = run;
#pragma unroll
    for (int off = 1; off < 64; off <<= 1) {
        int v = __shfl_up(incl, off, 64);
        if (l >= off) incl += v;
    }
    const int pre = incl - run;                // exclusive prefix of lane

    // block's 4 phonemes (4blk..4blk+3) live in lane L at i-offset 4*(blk&1)
    const int L = blk >> 1;
    int sm1, sa0, sa1, sa2, sa3;               // s[i0-1], s[i0..i0+3] of lane L
    if (blk & 1) {
        sm1 = __shfl(s[3], L, 64);
        sa0 = __shfl(s[4], L, 64); sa1 = __shfl(s[5], L, 64);
        sa2 = __shfl(s[6], L, 64); sa3 = __shfl(s[7], L, 64);
    } else {
        sm1 = 0;
        sa0 = __shfl(s[0], L, 64); sa1 = __shfl(s[1], L, 64);
        sa2 = __shfl(s[2], L, 64); sa3 = __shfl(s[3], L, 64);
    }
    const int preL  = __shfl(pre, L, 64);
    const int total = __shfl(incl, 63, 64);    // cum[511]

    const int st0 = preL + sm1;                // global start frame of ph 4blk
    const int d0 = sa0 - sm1, d1 = sa1 - sa0, d2 = sa2 - sa1, d3 = sa3 - sa2;

    // ---- store streams: rows x durations, zero loads in the stream ----
    int start, na, nb;
    if (sub == 0) { start = st0;           na = d0; nb = d1; }
    else          { start = st0 + d0 + d1; na = d2; nb = d3; }

    float4* outb = out + (size_t)b * MAX_LEN * (DD / 4) + lane;
    size_t p = (size_t)start * (DD / 4);
    for (int k = 0; k < na; ++k) { outb[p] = va; p += DD / 4; }
    for (int k = 0; k < nb; ++k) { outb[p] = vb; p += DD / 4; }

    // ---- padding [total, MAX_LEN): even slices across the batch's blocks ----
    const int pad = MAX_LEN - total;
    const int q0  = total + ((pad * blk) >> 7);
    const int q1  = total + ((pad * (blk + 1)) >> 7);
    const int h   = q1 - q0;
    const int mid = q0 + ((h + 1) >> 1);
    const int z0  = sub == 0 ? q0 : mid;
    const int z1  = sub == 0 ? mid : q1;
    const float4 zero = make_float4(0.f, 0.f, 0.f, 0.f);
    p = (size_t)z0 * (DD / 4);
    for (int k = z0; k < z1; ++k) { outb[p] = zero; p += DD / 4; }
}

extern "C" void kernel_launch(void* const* d_in, const int* in_sizes, int n_in,
                              void* d_out, int out_size, void* d_ws, size_t ws_size,
                              hipStream_t stream) {
    // Select pointers by element count (features = B*T*D = 2097152, dur = 4096)
    const float* feat;
    const int*   dur;
    if (in_sizes[0] == BB * TT) {
        dur  = (const int*)d_in[0];
        feat = (const float*)d_in[1];
    } else {
        feat = (const float*)d_in[0];
        dur  = (const int*)d_in[1];
    }
    float* out = (float*)d_out;        // (B, MAX_LEN, D) fp32

    regulate_kernel<<<BB * BPB, 256, 0, stream>>>(
        (const float4*)feat, dur, (float4*)out);
}